// Round 14
// baseline (676.718 us; speedup 1.0000x reference)
//
#include <hip/hip_runtime.h>
#include <cstdint>
#include <cstddef>

// ---------------------------------------------------------------------------
// BsPINN forward, single-fp16 MFMA (round 14).
// R12/R13 post-mortem: producer/consumer wave specialization loses to the
// plain two-barrier loop on this compiler (2 tries, both worse). Reverted.
// R14 vs R11: LDS-pipe is the binding constraint (~75% of layer-1 time at
// 88 KB/iter/block). B-fragments now load DIRECTLY from global (16B/lane,
// same address the LDS stage would produce; B working set 8 KB/block ->
// L1-resident, parallel pipe), prefetched one k-iter ahead. A stays
// LDS-staged (two-barrier backbone proven R10/R11). 128x128 tile, 4 waves.
//   h0 = tanh(norm(X) @ W0 + b0)        K=2   fp32 vector
//   h1 = tanh(h0 @ W1 + b1)             K=1024 MFMA f16
//   h2 = tanh(h1 @ (W2*m2) + b2)        2 x 512 block-diag (K=512)
//   out = tanh(h2 @ (W3*m3) + b3) @ W_last + b_last   (fused, K=256)
// fp16 error model validated R10/R11 (absmax 2.44e-4 << 9.2e-4).
// ---------------------------------------------------------------------------

typedef _Float16  f16x8   __attribute__((ext_vector_type(8)));
typedef float     floatx4 __attribute__((ext_vector_type(4)));
typedef float     floatx8 __attribute__((ext_vector_type(8)));

__device__ __forceinline__ float tanh_fast(float x) {
    float e = __expf(2.0f * x);
    return 1.0f - 2.0f / (e + 1.0f);
}

// ---------------------------------------------------------------------------
// Weight transpose + f16 convert, all three weights in one launch (z picks).
// ---------------------------------------------------------------------------
__global__ __launch_bounds__(256)
void transposeH3(const float* __restrict__ W1, const float* __restrict__ W2,
                 const float* __restrict__ W3, _Float16* __restrict__ Wt1,
                 _Float16* __restrict__ Wt2, _Float16* __restrict__ Wt3) {
    const float* W = blockIdx.z == 0 ? W1 : (blockIdx.z == 1 ? W2 : W3);
    _Float16* Wt   = blockIdx.z == 0 ? Wt1 : (blockIdx.z == 1 ? Wt2 : Wt3);
    __shared__ float tile[32][33];
    const int tx = threadIdx.x & 31;
    const int ty = threadIdx.x >> 5;     // 0..7
    #pragma unroll
    for (int j = 0; j < 4; ++j) {
        int r = ty + j * 8;
        tile[r][tx] = W[(size_t)(blockIdx.y * 32 + r) * 1024 + blockIdx.x * 32 + tx];
    }
    __syncthreads();
    #pragma unroll
    for (int j = 0; j < 4; ++j) {
        int r = ty + j * 8;
        Wt[(size_t)(blockIdx.x * 32 + r) * 1024 + blockIdx.y * 32 + tx] =
            (_Float16)tile[tx][r];
    }
}

// ---------------------------------------------------------------------------
// out[row] := b_last — re-initialized every call before layer3 atomics.
// ---------------------------------------------------------------------------
__global__ __launch_bounds__(256)
void init_out(float* __restrict__ out, const float* __restrict__ bl) {
    out[blockIdx.x * 256 + threadIdx.x] = bl[0];
}

// ---------------------------------------------------------------------------
// Layer 0 (fp32 in): h0 = tanh(xa*W0[0][:] + xb*W0[1][:] + b0) -> f16.
// ---------------------------------------------------------------------------
__global__ __launch_bounds__(256)
void layer0_kernel(const float* __restrict__ X, const float* __restrict__ W0,
                   const float* __restrict__ b0, _Float16* __restrict__ H) {
    const int idx = blockIdx.x * 256 + threadIdx.x;
    const int row = idx >> 7;
    const int j0  = (idx & 127) << 3;
    const float x0 = X[row * 2 + 0];
    const float x1 = X[row * 2 + 1];
    const float xa = x0 * 0.31830988618379067f - 1.0f;   // x0/pi - 1
    const float xb = 2.0f * x1 - 1.0f;
    floatx8 wa = *(const floatx8*)(W0 + j0);
    floatx8 wb = *(const floatx8*)(W0 + 1024 + j0);
    floatx8 bb = *(const floatx8*)(b0 + j0);
    f16x8 o;
    #pragma unroll
    for (int j = 0; j < 8; ++j) {
        float v = fmaf(xa, wa[j], fmaf(xb, wb[j], bb[j]));
        o[j] = (_Float16)tanh_fast(v);
    }
    *(f16x8*)(H + (size_t)row * 1024 + j0) = o;
}

// ---------------------------------------------------------------------------
// GEMM + bias + tanh, f16. 128x128 tile, 256 threads = 4 waves (2m x 2n),
// 4x4 16x16x32 frags/wave. BK=32 two-barrier K-loop.
// A: LDS-staged with register prefetch of tile t+1 (R11 pattern).
// B: fragments loaded DIRECTLY from global (16B/lane), double-registered,
// prefetched one iter ahead (issued before the MFMA block; L1-resident).
// KB = diag block: cols [n0,n0+128) need k in [(n0/KB)*KB, +KB).
// FUSE: layer3+final — tanh(pre).Wl partial, 16-lane shfl reduce, one fp32
// atomicAdd per row (out pre-initialized to b_last).
// ---------------------------------------------------------------------------
template <bool FUSE>
__global__ __launch_bounds__(256)
void gemm_tanh_f16(const _Float16* __restrict__ A, const _Float16* __restrict__ Bt,
                   const float* __restrict__ bias, _Float16* __restrict__ C,
                   const float* __restrict__ Wl, float* __restrict__ out, int KB) {
    __shared__ _Float16 As[128 * 32];   // 8 KB (A only)

    const int tid  = threadIdx.x;
    const int lane = tid & 63;
    const int wave = tid >> 6;           // 0..3
    const int m0 = blockIdx.x * 128;     // m fast (proven cache order)
    const int n0 = blockIdx.y * 128;
    const int kbeg   = (n0 / KB) * KB;
    const int kiters = KB >> 5;
    const int wm = (wave & 1) << 6;
    const int wn = (wave >> 1) << 6;
    const int r = lane & 15;
    const int q = lane >> 4;

    // A staging: 512 16B slots (128 rows x 4 segs), 2 per thread.
    const int rowS = tid >> 2;
    const int seg  = (tid & 3) << 3;
    const size_t gA0 = (size_t)(m0 + rowS) * 1024 + kbeg + seg;
    const size_t gA1 = gA0 + (size_t)64 * 1024;     // rows 64..127
    const int ldsA0 = tid * 8;
    const int ldsA1 = (256 + tid) * 8;

    // B fragment base (per lane): row n0+wn+j*16+r, elems kbeg + q*8.
    const size_t gB = (size_t)(n0 + wn + r) * 1024 + kbeg + q * 8;

    floatx4 acc[4][4];
    #pragma unroll
    for (int i = 0; i < 4; ++i)
        #pragma unroll
        for (int j = 0; j < 4; ++j)
            acc[i][j] = floatx4{0.f, 0.f, 0.f, 0.f};

    // Prologue: A tile 0 -> regs; B frags tile 0 -> regs.
    f16x8 va0 = *(const f16x8*)(A + gA0);
    f16x8 va1 = *(const f16x8*)(A + gA1);
    f16x8 bc[4], bn[4];
    #pragma unroll
    for (int j = 0; j < 4; ++j)
        bc[j] = *(const f16x8*)(Bt + gB + (size_t)j * 16384);

    for (int t = 0; t < kiters; ++t) {
        __syncthreads();                 // prior iter's ds_reads done
        *(f16x8*)(As + ldsA0) = va0;
        *(f16x8*)(As + ldsA1) = va1;
        __syncthreads();                 // A tile t visible

        if (t + 1 < kiters) {            // prefetch t+1 (overlaps MFMA)
            const size_t d = (size_t)(t + 1) << 5;
            va0 = *(const f16x8*)(A + gA0 + d);
            va1 = *(const f16x8*)(A + gA1 + d);
            #pragma unroll
            for (int j = 0; j < 4; ++j)
                bn[j] = *(const f16x8*)(Bt + gB + (size_t)j * 16384 + d);
        }

        f16x8 af[4];
        #pragma unroll
        for (int i = 0; i < 4; ++i)
            af[i] = *(const f16x8*)(As + (wm + i * 16 + r) * 32 + q * 8);
        #pragma unroll
        for (int i = 0; i < 4; ++i)
            #pragma unroll
            for (int j = 0; j < 4; ++j)
                acc[i][j] = __builtin_amdgcn_mfma_f32_16x16x32_f16(af[i], bc[j], acc[i][j], 0, 0, 0);
        #pragma unroll
        for (int j = 0; j < 4; ++j)
            bc[j] = bn[j];
    }

    // Epilogue. C/D layout: col=lane&15, row=(lane>>4)*4+reg.
    float bv[4], wlv[4];
    #pragma unroll
    for (int j = 0; j < 4; ++j) {
        const int col = n0 + wn + j * 16 + r;
        bv[j] = bias[col];
        if (FUSE) wlv[j] = Wl[col];
    }
    #pragma unroll
    for (int i = 0; i < 4; ++i) {
        const int row0 = m0 + wm + i * 16 + q * 4;
        #pragma unroll
        for (int rr = 0; rr < 4; ++rr) {
            if (!FUSE) {
                #pragma unroll
                for (int j = 0; j < 4; ++j) {
                    float o = tanh_fast(acc[i][j][rr] + bv[j]);
                    const int col = n0 + wn + j * 16 + r;
                    C[(size_t)(row0 + rr) * 1024 + col] = (_Float16)o;
                }
            } else {
                float p = 0.f;
                #pragma unroll
                for (int j = 0; j < 4; ++j)
                    p = fmaf(tanh_fast(acc[i][j][rr] + bv[j]), wlv[j], p);
                p += __shfl_down(p, 8);  // reduce the 16 r-lanes
                p += __shfl_down(p, 4);
                p += __shfl_down(p, 2);
                p += __shfl_down(p, 1);
                if (r == 0) atomicAdd(out + row0 + rr, p);
            }
        }
    }
}

// ---------------------------------------------------------------------------
extern "C" void kernel_launch(void* const* d_in, const int* in_sizes, int n_in,
                              void* d_out, int out_size, void* d_ws, size_t ws_size,
                              hipStream_t stream) {
    const float* X  = (const float*)d_in[0];
    const float* W0 = (const float*)d_in[1];
    const float* b0 = (const float*)d_in[2];
    const float* W1 = (const float*)d_in[3];
    const float* b1 = (const float*)d_in[4];
    const float* W2 = (const float*)d_in[5];
    const float* b2 = (const float*)d_in[6];
    const float* W3 = (const float*)d_in[7];
    const float* b3 = (const float*)d_in[8];
    const float* Wl = (const float*)d_in[9];
    const float* bl = (const float*)d_in[10];
    float* out = (float*)d_out;

    const int Nrows = in_sizes[0] / 2;                 // 65536
    const size_t WT = 1024 * 1024;                     // elems per f16 weight plane
    const size_t wt_bytes = 3 * WT * 2;                // 6 MiB
    const size_t slack = 512;

    // chunk rows R (pow2, capped 32768 so planes stay L3-resident).
    int R = 0;
    const int Rcap = Nrows < 32768 ? Nrows : 32768;
    for (int r = Rcap; r >= 256; r >>= 1)
        if ((size_t)2 * r * 2048 + wt_bytes + slack <= ws_size) { R = r; break; }
    if (!R) return;

    _Float16* wsp = (_Float16*)d_ws;
    _Float16* Wt1 = wsp;
    _Float16* Wt2 = Wt1 + WT;
    _Float16* Wt3 = Wt2 + WT;
    const size_t plane = (size_t)R * 1024;
    _Float16* P0 = Wt3 + WT;
    _Float16* P1 = P0 + plane;

    const dim3 tb(256);
    transposeH3<<<dim3(32, 32, 3), tb, 0, stream>>>(W1, W2, W3, Wt1, Wt2, Wt3);
    init_out<<<Nrows / 256, tb, 0, stream>>>(out, bl);

    const int nchunks = Nrows / R;
    for (int c = 0; c < nchunks; ++c) {
        const float* Xc = X + (size_t)c * R * 2;
        float* outc = out + (size_t)c * R;

        layer0_kernel<<<R / 2, tb, 0, stream>>>(Xc, W0, b0, P0);

        const dim3 gg(R / 128, 8);                    // m fast
        gemm_tanh_f16<false><<<gg, tb, 0, stream>>>(P0, Wt1, b1, P1, nullptr, nullptr, 1024);
        gemm_tanh_f16<false><<<gg, tb, 0, stream>>>(P1, Wt2, b2, P0, nullptr, nullptr, 512);
        gemm_tanh_f16<true ><<<gg, tb, 0, stream>>>(P0, Wt3, b3, nullptr, Wl, outc, 256);
    }
}

// Round 15
// 591.351 us; speedup vs baseline: 1.1444x; 1.1444x over previous
//
#include <hip/hip_runtime.h>
#include <cstdint>
#include <cstddef>

// ---------------------------------------------------------------------------
// BsPINN forward, single-fp16 MFMA (round 15).
// R12/R13/R14 all lost to R11's plain two-barrier loop (producer waves,
// raw-barrier pipelining, B-direct-global). R15 = R11 restored + ONE change:
// BK=64 (half the barrier crossings, 32 MFMAs per barrier-pair, same LDS
// byte totals). init_out folded into the transpose launch.
//   h0 = tanh(norm(X) @ W0 + b0)        K=2   fp32 vector
//   h1 = tanh(h0 @ W1 + b1)             K=1024 MFMA f16
//   h2 = tanh(h1 @ (W2*m2) + b2)        2 x 512 block-diag (K=512)
//   out = tanh(h2 @ (W3*m3) + b3) @ W_last + b_last   (fused, K=256)
// fp16 error model validated R10/R11 (absmax 2.44e-4 << 9.2e-4).
// ---------------------------------------------------------------------------

typedef _Float16  f16x8   __attribute__((ext_vector_type(8)));
typedef float     floatx4 __attribute__((ext_vector_type(4)));
typedef float     floatx8 __attribute__((ext_vector_type(8)));

__device__ __forceinline__ float tanh_fast(float x) {
    float e = __expf(2.0f * x);
    return 1.0f - 2.0f / (e + 1.0f);
}

// ---------------------------------------------------------------------------
// z<3: weight transpose + f16 convert (fp32 W[K][N] -> f16 Wt[N][K]).
// z==3: out[.] := b_last (re-init every call; layer3 atomics accumulate).
// ---------------------------------------------------------------------------
__global__ __launch_bounds__(256)
void transposeH3(const float* __restrict__ W1, const float* __restrict__ W2,
                 const float* __restrict__ W3, _Float16* __restrict__ Wt1,
                 _Float16* __restrict__ Wt2, _Float16* __restrict__ Wt3,
                 float* __restrict__ out, const float* __restrict__ bl,
                 int nrows) {
    if (blockIdx.z == 3) {
        const int id = (blockIdx.y * 32 + blockIdx.x) * 256 + threadIdx.x;
        if (id * 1 < nrows) out[id] = bl[0];
        return;
    }
    const float* W = blockIdx.z == 0 ? W1 : (blockIdx.z == 1 ? W2 : W3);
    _Float16* Wt   = blockIdx.z == 0 ? Wt1 : (blockIdx.z == 1 ? Wt2 : Wt3);
    __shared__ float tile[32][33];
    const int tx = threadIdx.x & 31;
    const int ty = threadIdx.x >> 5;     // 0..7
    #pragma unroll
    for (int j = 0; j < 4; ++j) {
        int r = ty + j * 8;
        tile[r][tx] = W[(size_t)(blockIdx.y * 32 + r) * 1024 + blockIdx.x * 32 + tx];
    }
    __syncthreads();
    #pragma unroll
    for (int j = 0; j < 4; ++j) {
        int r = ty + j * 8;
        Wt[(size_t)(blockIdx.x * 32 + r) * 1024 + blockIdx.y * 32 + tx] =
            (_Float16)tile[tx][r];
    }
}

// ---------------------------------------------------------------------------
// Layer 0 (fp32 in): h0 = tanh(xa*W0[0][:] + xb*W0[1][:] + b0) -> f16.
// ---------------------------------------------------------------------------
__global__ __launch_bounds__(256)
void layer0_kernel(const float* __restrict__ X, const float* __restrict__ W0,
                   const float* __restrict__ b0, _Float16* __restrict__ H) {
    const int idx = blockIdx.x * 256 + threadIdx.x;
    const int row = idx >> 7;
    const int j0  = (idx & 127) << 3;
    const float x0 = X[row * 2 + 0];
    const float x1 = X[row * 2 + 1];
    const float xa = x0 * 0.31830988618379067f - 1.0f;   // x0/pi - 1
    const float xb = 2.0f * x1 - 1.0f;
    floatx8 wa = *(const floatx8*)(W0 + j0);
    floatx8 wb = *(const floatx8*)(W0 + 1024 + j0);
    floatx8 bb = *(const floatx8*)(b0 + j0);
    f16x8 o;
    #pragma unroll
    for (int j = 0; j < 8; ++j) {
        float v = fmaf(xa, wa[j], fmaf(xb, wb[j], bb[j]));
        o[j] = (_Float16)tanh_fast(v);
    }
    *(f16x8*)(H + (size_t)row * 1024 + j0) = o;
}

// ---------------------------------------------------------------------------
// GEMM + bias + tanh, f16. 256x128 tile, 512 threads = 8 waves (4m x 2n),
// each wave 64x64 via 4x4 16x16x32 frags. BK=64: two 32-k sub-steps per
// barrier-pair (32 MFMAs/wave between barriers). Register prefetch of
// tile t+1 overlaps the MFMA block (R11 pattern).
// KB = diag block: cols [n0,n0+128) need k in [(n0/KB)*KB, +KB).
// FUSE: layer3+final — tanh(pre).Wl partial, 16-lane shfl reduce, one fp32
// atomicAdd per row (out pre-initialized to b_last).
// ---------------------------------------------------------------------------
template <bool FUSE>
__global__ __launch_bounds__(512)
void gemm_tanh_f16(const _Float16* __restrict__ A, const _Float16* __restrict__ Bt,
                   const float* __restrict__ bias, _Float16* __restrict__ C,
                   const float* __restrict__ Wl, float* __restrict__ out, int KB) {
    __shared__ _Float16 As[256 * 64];   // 32 KB
    __shared__ _Float16 Bs[128 * 64];   // 16 KB

    const int tid  = threadIdx.x;
    const int lane = tid & 63;
    const int wave = tid >> 6;
    const int m0 = blockIdx.x * 256;          // m fast (proven cache order)
    const int n0 = blockIdx.y * 128;
    const int kbeg   = (n0 / KB) * KB;
    const int kiters = KB >> 6;               // BK=64
    const int wm = (wave & 3) << 6;           // 0,64,128,192
    const int wn = (wave >> 2) << 6;          // 0,64
    const int r = lane & 15;
    const int q = lane >> 4;

    // Staging: A 2048 16B slots (4/thread), B 1024 slots (2/thread).
    // slot s: row = s>>3, seg = (s&7)*8 elems; s = tid + 512*i.
    const int rowS = tid >> 3;                // 0..63
    const int segS = (tid & 7) << 3;          // 0..56
    const size_t gA = (size_t)(m0 + rowS) * 1024 + kbeg + segS;
    const size_t gB = (size_t)(n0 + rowS) * 1024 + kbeg + segS;
    const int ldsS = tid * 8;                 // +4096 elems per i

    floatx4 acc[4][4];
    #pragma unroll
    for (int i = 0; i < 4; ++i)
        #pragma unroll
        for (int j = 0; j < 4; ++j)
            acc[i][j] = floatx4{0.f, 0.f, 0.f, 0.f};

    // Prologue: k-tile 0 into regs (A rows stride 64 per i, B stride 64 per i).
    f16x8 va[4], vb[2];
    #pragma unroll
    for (int i = 0; i < 4; ++i) va[i] = *(const f16x8*)(A + gA + (size_t)i * 65536);
    #pragma unroll
    for (int i = 0; i < 2; ++i) vb[i] = *(const f16x8*)(Bt + gB + (size_t)i * 65536);

    for (int t = 0; t < kiters; ++t) {
        __syncthreads();                      // prior iter's ds_reads done
        #pragma unroll
        for (int i = 0; i < 4; ++i) *(f16x8*)(As + ldsS + i * 4096) = va[i];
        #pragma unroll
        for (int i = 0; i < 2; ++i) *(f16x8*)(Bs + ldsS + i * 4096) = vb[i];
        __syncthreads();                      // tile t visible

        if (t + 1 < kiters) {                 // prefetch t+1 (overlaps MFMA)
            const size_t d = (size_t)(t + 1) << 6;
            #pragma unroll
            for (int i = 0; i < 4; ++i) va[i] = *(const f16x8*)(A + gA + (size_t)i * 65536 + d);
            #pragma unroll
            for (int i = 0; i < 2; ++i) vb[i] = *(const f16x8*)(Bt + gB + (size_t)i * 65536 + d);
        }

        #pragma unroll
        for (int sub = 0; sub < 2; ++sub) {
            f16x8 af[4], bf[4];
            #pragma unroll
            for (int i = 0; i < 4; ++i) {
                af[i] = *(const f16x8*)(As + (wm + i * 16 + r) * 64 + sub * 32 + q * 8);
                bf[i] = *(const f16x8*)(Bs + (wn + i * 16 + r) * 64 + sub * 32 + q * 8);
            }
            #pragma unroll
            for (int i = 0; i < 4; ++i)
                #pragma unroll
                for (int j = 0; j < 4; ++j)
                    acc[i][j] = __builtin_amdgcn_mfma_f32_16x16x32_f16(af[i], bf[j], acc[i][j], 0, 0, 0);
        }
    }

    // Epilogue. C/D layout: col=lane&15, row=(lane>>4)*4+reg.
    float bv[4], wlv[4];
    #pragma unroll
    for (int j = 0; j < 4; ++j) {
        const int col = n0 + wn + j * 16 + r;
        bv[j] = bias[col];
        if (FUSE) wlv[j] = Wl[col];
    }
    #pragma unroll
    for (int i = 0; i < 4; ++i) {
        const int row0 = m0 + wm + i * 16 + q * 4;
        #pragma unroll
        for (int rr = 0; rr < 4; ++rr) {
            if (!FUSE) {
                #pragma unroll
                for (int j = 0; j < 4; ++j) {
                    float o = tanh_fast(acc[i][j][rr] + bv[j]);
                    const int col = n0 + wn + j * 16 + r;
                    C[(size_t)(row0 + rr) * 1024 + col] = (_Float16)o;
                }
            } else {
                float p = 0.f;
                #pragma unroll
                for (int j = 0; j < 4; ++j)
                    p = fmaf(tanh_fast(acc[i][j][rr] + bv[j]), wlv[j], p);
                p += __shfl_down(p, 8);  // reduce the 16 r-lanes
                p += __shfl_down(p, 4);
                p += __shfl_down(p, 2);
                p += __shfl_down(p, 1);
                if (r == 0) atomicAdd(out + row0 + rr, p);
            }
        }
    }
}

// ---------------------------------------------------------------------------
extern "C" void kernel_launch(void* const* d_in, const int* in_sizes, int n_in,
                              void* d_out, int out_size, void* d_ws, size_t ws_size,
                              hipStream_t stream) {
    const float* X  = (const float*)d_in[0];
    const float* W0 = (const float*)d_in[1];
    const float* b0 = (const float*)d_in[2];
    const float* W1 = (const float*)d_in[3];
    const float* b1 = (const float*)d_in[4];
    const float* W2 = (const float*)d_in[5];
    const float* b2 = (const float*)d_in[6];
    const float* W3 = (const float*)d_in[7];
    const float* b3 = (const float*)d_in[8];
    const float* Wl = (const float*)d_in[9];
    const float* bl = (const float*)d_in[10];
    float* out = (float*)d_out;

    const int Nrows = in_sizes[0] / 2;                 // 65536
    const size_t WT = 1024 * 1024;                     // elems per f16 weight plane
    const size_t wt_bytes = 3 * WT * 2;                // 6 MiB
    const size_t slack = 512;

    // chunk rows R (pow2, capped 32768 so planes stay L3-resident).
    int R = 0;
    const int Rcap = Nrows < 32768 ? Nrows : 32768;
    for (int r = Rcap; r >= 256; r >>= 1)
        if ((size_t)2 * r * 2048 + wt_bytes + slack <= ws_size) { R = r; break; }
    if (!R) return;

    _Float16* wsp = (_Float16*)d_ws;
    _Float16* Wt1 = wsp;
    _Float16* Wt2 = Wt1 + WT;
    _Float16* Wt3 = Wt2 + WT;
    const size_t plane = (size_t)R * 1024;
    _Float16* P0 = Wt3 + WT;
    _Float16* P1 = P0 + plane;

    const dim3 tb(256);
    transposeH3<<<dim3(32, 32, 4), tb, 0, stream>>>(W1, W2, W3, Wt1, Wt2, Wt3,
                                                    out, bl, Nrows);

    const int nchunks = Nrows / R;
    for (int c = 0; c < nchunks; ++c) {
        const float* Xc = X + (size_t)c * R * 2;
        float* outc = out + (size_t)c * R;

        layer0_kernel<<<R / 2, tb, 0, stream>>>(Xc, W0, b0, P0);

        const dim3 tg(512);
        const dim3 gg(R / 256, 8);                    // m fast
        gemm_tanh_f16<false><<<gg, tg, 0, stream>>>(P0, Wt1, b1, P1, nullptr, nullptr, 1024);
        gemm_tanh_f16<false><<<gg, tg, 0, stream>>>(P1, Wt2, b2, P0, nullptr, nullptr, 512);
        gemm_tanh_f16<true ><<<gg, tg, 0, stream>>>(P0, Wt3, b3, nullptr, Wl, outc, 256);
    }
}

// Round 16
// 549.452 us; speedup vs baseline: 1.2316x; 1.0763x over previous
//
#include <hip/hip_runtime.h>
#include <cstdint>
#include <cstddef>

// ---------------------------------------------------------------------------
// BsPINN forward, single-fp16 MFMA (round 16).
// R15 post-mortem: BK=64 made the LDS row stride 128 B == 0 mod 128 B, all
// 16 r-lanes of a fragment read started at the same bank -> 2.5e7 conflicts
// (3x R11) and the regression. R16 = R15 + row padding to 72 elems (144 B):
// start bank = 4*(r+q) mod 32, balanced 8 dwords/bank (structural minimum).
// Everything else identical to R15 (BK=64, 256x128 tile, 8 waves, fused
// layer3+final, two-barrier K-loop with register prefetch).
//   h0 = tanh(norm(X) @ W0 + b0)        K=2   fp32 vector
//   h1 = tanh(h0 @ W1 + b1)             K=1024 MFMA f16
//   h2 = tanh(h1 @ (W2*m2) + b2)        2 x 512 block-diag (K=512)
//   out = tanh(h2 @ (W3*m3) + b3) @ W_last + b_last   (fused, K=256)
// fp16 error model validated R10/R11 (absmax 2.44e-4 << 9.2e-4).
// ---------------------------------------------------------------------------

typedef _Float16  f16x8   __attribute__((ext_vector_type(8)));
typedef float     floatx4 __attribute__((ext_vector_type(4)));
typedef float     floatx8 __attribute__((ext_vector_type(8)));

#define SA 72   // padded LDS row stride in elems (144 B; 64 data + 8 pad)

__device__ __forceinline__ float tanh_fast(float x) {
    float e = __expf(2.0f * x);
    return 1.0f - 2.0f / (e + 1.0f);
}

// ---------------------------------------------------------------------------
// z<3: weight transpose + f16 convert (fp32 W[K][N] -> f16 Wt[N][K]).
// z==3: out[.] := b_last (re-init every call; layer3 atomics accumulate).
// ---------------------------------------------------------------------------
__global__ __launch_bounds__(256)
void transposeH3(const float* __restrict__ W1, const float* __restrict__ W2,
                 const float* __restrict__ W3, _Float16* __restrict__ Wt1,
                 _Float16* __restrict__ Wt2, _Float16* __restrict__ Wt3,
                 float* __restrict__ out, const float* __restrict__ bl,
                 int nrows) {
    if (blockIdx.z == 3) {
        const int id = (blockIdx.y * 32 + blockIdx.x) * 256 + threadIdx.x;
        if (id < nrows) out[id] = bl[0];
        return;
    }
    const float* W = blockIdx.z == 0 ? W1 : (blockIdx.z == 1 ? W2 : W3);
    _Float16* Wt   = blockIdx.z == 0 ? Wt1 : (blockIdx.z == 1 ? Wt2 : Wt3);
    __shared__ float tile[32][33];
    const int tx = threadIdx.x & 31;
    const int ty = threadIdx.x >> 5;     // 0..7
    #pragma unroll
    for (int j = 0; j < 4; ++j) {
        int r = ty + j * 8;
        tile[r][tx] = W[(size_t)(blockIdx.y * 32 + r) * 1024 + blockIdx.x * 32 + tx];
    }
    __syncthreads();
    #pragma unroll
    for (int j = 0; j < 4; ++j) {
        int r = ty + j * 8;
        Wt[(size_t)(blockIdx.x * 32 + r) * 1024 + blockIdx.y * 32 + tx] =
            (_Float16)tile[tx][r];
    }
}

// ---------------------------------------------------------------------------
// Layer 0 (fp32 in): h0 = tanh(xa*W0[0][:] + xb*W0[1][:] + b0) -> f16.
// ---------------------------------------------------------------------------
__global__ __launch_bounds__(256)
void layer0_kernel(const float* __restrict__ X, const float* __restrict__ W0,
                   const float* __restrict__ b0, _Float16* __restrict__ H) {
    const int idx = blockIdx.x * 256 + threadIdx.x;
    const int row = idx >> 7;
    const int j0  = (idx & 127) << 3;
    const float x0 = X[row * 2 + 0];
    const float x1 = X[row * 2 + 1];
    const float xa = x0 * 0.31830988618379067f - 1.0f;   // x0/pi - 1
    const float xb = 2.0f * x1 - 1.0f;
    floatx8 wa = *(const floatx8*)(W0 + j0);
    floatx8 wb = *(const floatx8*)(W0 + 1024 + j0);
    floatx8 bb = *(const floatx8*)(b0 + j0);
    f16x8 o;
    #pragma unroll
    for (int j = 0; j < 8; ++j) {
        float v = fmaf(xa, wa[j], fmaf(xb, wb[j], bb[j]));
        o[j] = (_Float16)tanh_fast(v);
    }
    *(f16x8*)(H + (size_t)row * 1024 + j0) = o;
}

// ---------------------------------------------------------------------------
// GEMM + bias + tanh, f16. 256x128 tile, 512 threads = 8 waves (4m x 2n),
// each wave 64x64 via 4x4 16x16x32 frags. BK=64 (two 32-k sub-steps per
// barrier-pair, 32 MFMAs/wave between barriers). LDS rows padded to 72
// elems (bank-balanced). Register prefetch of tile t+1 overlaps MFMA.
// KB = diag block: cols [n0,n0+128) need k in [(n0/KB)*KB, +KB).
// FUSE: layer3+final — tanh(pre).Wl partial, 16-lane shfl reduce, one fp32
// atomicAdd per row (out pre-initialized to b_last).
// ---------------------------------------------------------------------------
template <bool FUSE>
__global__ __launch_bounds__(512)
void gemm_tanh_f16(const _Float16* __restrict__ A, const _Float16* __restrict__ Bt,
                   const float* __restrict__ bias, _Float16* __restrict__ C,
                   const float* __restrict__ Wl, float* __restrict__ out, int KB) {
    __shared__ _Float16 As[256 * SA];   // 36 KB
    __shared__ _Float16 Bs[128 * SA];   // 18 KB

    const int tid  = threadIdx.x;
    const int lane = tid & 63;
    const int wave = tid >> 6;
    const int m0 = blockIdx.x * 256;          // m fast (proven cache order)
    const int n0 = blockIdx.y * 128;
    const int kbeg   = (n0 / KB) * KB;
    const int kiters = KB >> 6;               // BK=64
    const int wm = (wave & 3) << 6;           // 0,64,128,192
    const int wn = (wave >> 2) << 6;          // 0,64
    const int r = lane & 15;
    const int q = lane >> 4;

    // Staging: slot s = tid + 512*i; row = s>>3 (64 rows per i-step),
    // seg = (s&7)*8. Global addr unchanged; LDS addr uses padded stride.
    const int rowS = tid >> 3;                // 0..63
    const int segS = (tid & 7) << 3;          // 0..56
    const size_t gA = (size_t)(m0 + rowS) * 1024 + kbeg + segS;
    const size_t gB = (size_t)(n0 + rowS) * 1024 + kbeg + segS;
    const int lw = rowS * SA + segS;          // + i*64*SA per i

    floatx4 acc[4][4];
    #pragma unroll
    for (int i = 0; i < 4; ++i)
        #pragma unroll
        for (int j = 0; j < 4; ++j)
            acc[i][j] = floatx4{0.f, 0.f, 0.f, 0.f};

    // Prologue: k-tile 0 into regs (rows stride 64 per i).
    f16x8 va[4], vb[2];
    #pragma unroll
    for (int i = 0; i < 4; ++i) va[i] = *(const f16x8*)(A + gA + (size_t)i * 65536);
    #pragma unroll
    for (int i = 0; i < 2; ++i) vb[i] = *(const f16x8*)(Bt + gB + (size_t)i * 65536);

    for (int t = 0; t < kiters; ++t) {
        __syncthreads();                      // prior iter's ds_reads done
        #pragma unroll
        for (int i = 0; i < 4; ++i) *(f16x8*)(As + lw + i * 64 * SA) = va[i];
        #pragma unroll
        for (int i = 0; i < 2; ++i) *(f16x8*)(Bs + lw + i * 64 * SA) = vb[i];
        __syncthreads();                      // tile t visible

        if (t + 1 < kiters) {                 // prefetch t+1 (overlaps MFMA)
            const size_t d = (size_t)(t + 1) << 6;
            #pragma unroll
            for (int i = 0; i < 4; ++i) va[i] = *(const f16x8*)(A + gA + (size_t)i * 65536 + d);
            #pragma unroll
            for (int i = 0; i < 2; ++i) vb[i] = *(const f16x8*)(Bt + gB + (size_t)i * 65536 + d);
        }

        #pragma unroll
        for (int sub = 0; sub < 2; ++sub) {
            f16x8 af[4], bf[4];
            #pragma unroll
            for (int i = 0; i < 4; ++i) {
                af[i] = *(const f16x8*)(As + (wm + i * 16 + r) * SA + sub * 32 + q * 8);
                bf[i] = *(const f16x8*)(Bs + (wn + i * 16 + r) * SA + sub * 32 + q * 8);
            }
            #pragma unroll
            for (int i = 0; i < 4; ++i)
                #pragma unroll
                for (int j = 0; j < 4; ++j)
                    acc[i][j] = __builtin_amdgcn_mfma_f32_16x16x32_f16(af[i], bf[j], acc[i][j], 0, 0, 0);
        }
    }

    // Epilogue. C/D layout: col=lane&15, row=(lane>>4)*4+reg.
    float bv[4], wlv[4];
    #pragma unroll
    for (int j = 0; j < 4; ++j) {
        const int col = n0 + wn + j * 16 + r;
        bv[j] = bias[col];
        if (FUSE) wlv[j] = Wl[col];
    }
    #pragma unroll
    for (int i = 0; i < 4; ++i) {
        const int row0 = m0 + wm + i * 16 + q * 4;
        #pragma unroll
        for (int rr = 0; rr < 4; ++rr) {
            if (!FUSE) {
                #pragma unroll
                for (int j = 0; j < 4; ++j) {
                    float o = tanh_fast(acc[i][j][rr] + bv[j]);
                    const int col = n0 + wn + j * 16 + r;
                    C[(size_t)(row0 + rr) * 1024 + col] = (_Float16)o;
                }
            } else {
                float p = 0.f;
                #pragma unroll
                for (int j = 0; j < 4; ++j)
                    p = fmaf(tanh_fast(acc[i][j][rr] + bv[j]), wlv[j], p);
                p += __shfl_down(p, 8);  // reduce the 16 r-lanes
                p += __shfl_down(p, 4);
                p += __shfl_down(p, 2);
                p += __shfl_down(p, 1);
                if (r == 0) atomicAdd(out + row0 + rr, p);
            }
        }
    }
}

// ---------------------------------------------------------------------------
extern "C" void kernel_launch(void* const* d_in, const int* in_sizes, int n_in,
                              void* d_out, int out_size, void* d_ws, size_t ws_size,
                              hipStream_t stream) {
    const float* X  = (const float*)d_in[0];
    const float* W0 = (const float*)d_in[1];
    const float* b0 = (const float*)d_in[2];
    const float* W1 = (const float*)d_in[3];
    const float* b1 = (const float*)d_in[4];
    const float* W2 = (const float*)d_in[5];
    const float* b2 = (const float*)d_in[6];
    const float* W3 = (const float*)d_in[7];
    const float* b3 = (const float*)d_in[8];
    const float* Wl = (const float*)d_in[9];
    const float* bl = (const float*)d_in[10];
    float* out = (float*)d_out;

    const int Nrows = in_sizes[0] / 2;                 // 65536
    const size_t WT = 1024 * 1024;                     // elems per f16 weight plane
    const size_t wt_bytes = 3 * WT * 2;                // 6 MiB
    const size_t slack = 512;

    // chunk rows R (pow2, capped 32768 so planes stay L3-resident).
    int R = 0;
    const int Rcap = Nrows < 32768 ? Nrows : 32768;
    for (int r = Rcap; r >= 256; r >>= 1)
        if ((size_t)2 * r * 2048 + wt_bytes + slack <= ws_size) { R = r; break; }
    if (!R) return;

    _Float16* wsp = (_Float16*)d_ws;
    _Float16* Wt1 = wsp;
    _Float16* Wt2 = Wt1 + WT;
    _Float16* Wt3 = Wt2 + WT;
    const size_t plane = (size_t)R * 1024;
    _Float16* P0 = Wt3 + WT;
    _Float16* P1 = P0 + plane;

    const dim3 tb(256);
    transposeH3<<<dim3(32, 32, 4), tb, 0, stream>>>(W1, W2, W3, Wt1, Wt2, Wt3,
                                                    out, bl, Nrows);

    const int nchunks = Nrows / R;
    for (int c = 0; c < nchunks; ++c) {
        const float* Xc = X + (size_t)c * R * 2;
        float* outc = out + (size_t)c * R;

        layer0_kernel<<<R / 2, tb, 0, stream>>>(Xc, W0, b0, P0);

        const dim3 tg(512);
        const dim3 gg(R / 256, 8);                    // m fast
        gemm_tanh_f16<false><<<gg, tg, 0, stream>>>(P0, Wt1, b1, P1, nullptr, nullptr, 1024);
        gemm_tanh_f16<false><<<gg, tg, 0, stream>>>(P1, Wt2, b2, P0, nullptr, nullptr, 512);
        gemm_tanh_f16<true ><<<gg, tg, 0, stream>>>(P0, Wt3, b3, nullptr, Wl, outc, 256);
    }
}